// Round 18
// baseline (263.586 us; speedup 1.0000x reference)
//
#include <hip/hip_runtime.h>

#define D 128
#define SC_IT 8    // edges per thread in scatter chunk (strided by 256)

typedef __attribute__((ext_vector_type(8))) short bf16x8;
typedef __attribute__((ext_vector_type(4))) float f32x4;
typedef __attribute__((ext_vector_type(4))) unsigned uint4v;

__device__ __forceinline__ float uif(unsigned u) { return __uint_as_float(u); }
__device__ __forceinline__ unsigned short f2bf(float f) {
    unsigned u = __float_as_uint(f);
    u += 0x7fffu + ((u >> 16) & 1u);     // RNE to bf16
    return (unsigned short)(u >> 16);
}
__device__ __forceinline__ float bf2f(unsigned short h) {
    return __uint_as_float(((unsigned)h) << 16);
}

// e4m3fn encode (software; N*128 values per layer — cheap)
__device__ __forceinline__ unsigned char f2fp8(float f) {
    unsigned s = (__float_as_uint(f) >> 24) & 0x80u;
    float a = fminf(fabsf(f), 448.f);
    unsigned b = __float_as_uint(a);
    int e = (int)((b >> 23) & 255) - 127;
    unsigned r;
    if (e >= -6) {
        unsigned rb = b + 0x7ffffu + ((b >> 20) & 1u);   // RNE to 3-bit mant
        int e8 = (int)((rb >> 23) & 255) - 120;
        unsigned m3 = (rb >> 20) & 7u;
        if (e8 > 15) { e8 = 15; m3 = 6; }                // clamp to 448
        r = ((unsigned)e8 << 3) | m3;
    } else {
        int ni = (int)(a * 512.f + 0.5f);                // denorm: k * 2^-9
        r = (ni > 7) ? 8u : (unsigned)ni;
    }
    return (unsigned char)(s | r);
}

#if __has_builtin(__builtin_amdgcn_cvt_pk_f32_fp8)
#define DECODE8(Q0, Q1, F)                                                      \
    do {                                                                        \
        auto p0 = __builtin_amdgcn_cvt_pk_f32_fp8((Q0), false);                 \
        auto p1 = __builtin_amdgcn_cvt_pk_f32_fp8((Q0), true);                  \
        auto p2 = __builtin_amdgcn_cvt_pk_f32_fp8((Q1), false);                 \
        auto p3 = __builtin_amdgcn_cvt_pk_f32_fp8((Q1), true);                  \
        (F)[0] = p0[0]; (F)[1] = p0[1]; (F)[2] = p1[0]; (F)[3] = p1[1];         \
        (F)[4] = p2[0]; (F)[5] = p2[1]; (F)[6] = p3[0]; (F)[7] = p3[1];         \
    } while (0)
#else
__device__ __forceinline__ float fp82f_sw(unsigned b) {
    unsigned e = (b >> 3) & 15u, m = b & 7u;
    float v = e ? uif(((e + 120u) << 23) | (m << 20)) : (float)m * 0x1p-9f;
    return (b & 0x80u) ? -v : v;
}
#define DECODE8(Q0, Q1, F)                                                      \
    do {                                                                        \
        unsigned q0 = (Q0), q1 = (Q1);                                          \
        (F)[0] = fp82f_sw(q0 & 255); (F)[1] = fp82f_sw((q0 >> 8) & 255);        \
        (F)[2] = fp82f_sw((q0 >> 16) & 255); (F)[3] = fp82f_sw(q0 >> 24);       \
        (F)[4] = fp82f_sw(q1 & 255); (F)[5] = fp82f_sw((q1 >> 8) & 255);        \
        (F)[6] = fp82f_sw((q1 >> 16) & 255); (F)[7] = fp82f_sw(q1 >> 24);       \
    } while (0)
#endif

// ---------------------------------------------------------------------------
// CSR build: flat rank histogram (R17 lesson: XCD-split just moves the
// ping-pong to sparse rank writes) -> scan -> XCD atomic-free scatter.
// edata entry: bits[15:0] = src (N < 65536), bits[31:16] = bf16(w).
// ---------------------------------------------------------------------------
__global__ __launch_bounds__(256) void rank_kernel(
    const int* __restrict__ dst, int* __restrict__ counts,
    int* __restrict__ rank, int E)
{
    int e = blockIdx.x * 256 + threadIdx.x;
    if (e < E) rank[e] = atomicAdd(&counts[dst[e]], 1);
}

__global__ __launch_bounds__(256) void blocksum_kernel(
    const int* __restrict__ counts, int* __restrict__ bsums, int N)
{
    __shared__ int red[256];
    int t = threadIdx.x;
    int i = blockIdx.x * 256 + t;
    red[t] = (i < N) ? counts[i] : 0;
    __syncthreads();
    #pragma unroll
    for (int off = 128; off > 0; off >>= 1) {
        if (t < off) red[t] += red[t + off];
        __syncthreads();
    }
    if (t == 0) bsums[blockIdx.x] = red[0];
}

__global__ __launch_bounds__(256) void scansums_kernel(
    int* __restrict__ bsums, int nb)
{
    __shared__ int s[256];
    int t = threadIdx.x;
    int v = (t < nb) ? bsums[t] : 0;
    s[t] = v;
    __syncthreads();
    #pragma unroll
    for (int off = 1; off < 256; off <<= 1) {
        int tmp = (t >= off) ? s[t - off] : 0;
        __syncthreads();
        s[t] += tmp;
        __syncthreads();
    }
    if (t < nb) bsums[t] = s[t] - v;
}

__global__ __launch_bounds__(256) void emit_kernel(
    const int* __restrict__ counts, const int* __restrict__ bsums,
    int* __restrict__ row_ptr, int N, int E)
{
    __shared__ int s[256];
    int t = threadIdx.x;
    int i = blockIdx.x * 256 + t;
    int v = (i < N) ? counts[i] : 0;
    s[t] = v;
    __syncthreads();
    #pragma unroll
    for (int off = 1; off < 256; off <<= 1) {
        int tmp = (t >= off) ? s[t - off] : 0;
        __syncthreads();
        s[t] += tmp;
        __syncthreads();
    }
    int excl = s[t] - v + bsums[blockIdx.x];
    if (i < N) row_ptr[i] = excl;
    if (blockIdx.x == 0 && t == 0) row_ptr[N] = E;
}

// XCD-partitioned atomic-free scatter (stride-1 lane->edge mapping, R12).
__global__ __launch_bounds__(256) void scatter_xcd_kernel(
    const int* __restrict__ src, const int* __restrict__ dst,
    const float* __restrict__ ew, const int* __restrict__ row_ptr,
    const int* __restrict__ rank, unsigned* __restrict__ edata, int E, int N)
{
    int xcd   = blockIdx.x & 7;
    int chunk = blockIdx.x >> 3;
    int lo = (int)(((long long)xcd * N) >> 3);
    int hi = (int)(((long long)(xcd + 1) * N) >> 3);
    int base = chunk * (256 * SC_IT) + threadIdx.x;
    #pragma unroll
    for (int it = 0; it < SC_IT; ++it) {
        int e = base + it * 256;
        if (e < E) {
            int d = __builtin_nontemporal_load(&dst[e]);
            if (d >= lo && d < hi) {
                int pos = row_ptr[d] + rank[e];
                unsigned pk = (unsigned)(unsigned short)
                                  __builtin_nontemporal_load(&src[e])
                            | ((unsigned)f2bf(
                                  __builtin_nontemporal_load(&ew[e])) << 16);
                edata[pos] = pk;
            }
        }
    }
}

// ---------------------------------------------------------------------------
// Converts. h: bf16 [Npad][128] (gemm operand) + fp8 e4m3fn [Npad][128]
// (gather operand). Both ping-pong across layers.
// WT: [L][128 cols][256 k] bf16; k 0-127 = Wrel rows, 128-255 = Wroot.
// ---------------------------------------------------------------------------
__global__ __launch_bounds__(256) void convert_x_kernel(
    const float* __restrict__ x, short* __restrict__ Ah,
    unsigned char* __restrict__ Ah8, int N)
{
    int t = blockIdx.x * 256 + threadIdx.x;   // over N*64 (pairs of cols)
    if (t >= N * 64) return;
    int row = t >> 6;
    int c2  = (t & 63) * 2;
    float2 v = *(const float2*)(x + (size_t)row * D + c2);
    *(unsigned*)(Ah + (size_t)row * D + c2) =
        ((unsigned)f2bf(v.y) << 16) | f2bf(v.x);
    unsigned short p8 = (unsigned short)f2fp8(v.x)
                      | ((unsigned short)f2fp8(v.y) << 8);
    *(unsigned short*)(Ah8 + (size_t)row * D + c2) = p8;
}

__global__ __launch_bounds__(256) void convert_w_kernel(
    const float* __restrict__ Wrel, const float* __restrict__ Wroot,
    short* __restrict__ WT, int total)
{
    int t = blockIdx.x * 256 + threadIdx.x;   // over L*32768
    if (t >= total) return;
    int l = t >> 15;
    int rem = t & 32767;
    int k = rem >> 7;
    int c = rem & 127;
    float f = (k < 128) ? Wrel[(size_t)l * 16384 + k * D + c]
                        : Wroot[(size_t)l * 16384 + (k - 128) * D + c];
    WT[(size_t)l * 32768 + c * 256 + k] = (short)f2bf(f);
}

// ---------------------------------------------------------------------------
// Aggregation: one wave per node, 8 x 8-lane groups. Group g loads edge
// (j+g)'s whole fp8 row as dwordx4/lane (16B = 16 cols/lane, 8 lanes/row).
// R17 lesson: gather is ADDRESS-count-bound, not byte-bound — halving
// lanes-per-edge (16 -> 8) halves the TA address work per edge.
// CONVERGENT inner loop (R6). Packed 4B edges: src=lo16, bf16 w=hi16.
// Fold 8 groups via shfl_xor(8,16,32); group 0 writes aggHi bf16.
// ---------------------------------------------------------------------------
__global__ __launch_bounds__(256) void gather_fp8(
    const unsigned char* __restrict__ Ah8, short* __restrict__ aggHi,
    const unsigned* __restrict__ edata, const int* __restrict__ row_ptr, int N)
{
    int wave = (blockIdx.x * 256 + threadIdx.x) >> 6;
    int lane = threadIdx.x & 63;
    if (wave >= N) return;
    int g  = lane >> 3;         // group 0..7
    int l8 = lane & 7;          // lane within group
    int beg = row_ptr[wave];
    int cnt = row_ptr[wave + 1] - beg;

    const unsigned char* hbase = Ah8 + l8 * 16;   // this lane's 16 cols

    float acc[16];
    #pragma unroll
    for (int c = 0; c < 16; ++c) acc[c] = 0.f;

    for (int base = 0; base < cnt; base += 64) {
        int k = base + lane;
        int ed = 0;                              // padding: src=0, w=+0.0f
        if (k < cnt) ed = (int)edata[beg + k];
        int m = min(64, cnt - base);
        // convergent: j <= 48, so j+8+g <= 63 is a valid lane; edges past m
        // come from padding lanes (w=0) and contribute nothing.
        for (int j = 0; j < m; j += 16) {
            int eA = __shfl(ed, j + g);
            int eB = __shfl(ed, j + 8 + g);
            float wA = uif((unsigned)eA & 0xffff0000u);
            float wB = uif((unsigned)eB & 0xffff0000u);
            uint4v qA = *(const uint4v*)(hbase + (size_t)(eA & 0xffff) * D);
            uint4v qB = *(const uint4v*)(hbase + (size_t)(eB & 0xffff) * D);
            float fA[16], fB[16];
            DECODE8(qA.x, qA.y, fA);
            DECODE8(qA.z, qA.w, fA + 8);
            DECODE8(qB.x, qB.y, fB);
            DECODE8(qB.z, qB.w, fB + 8);
            #pragma unroll
            for (int c = 0; c < 16; ++c) acc[c] = fmaf(wA, fA[c], acc[c]);
            #pragma unroll
            for (int c = 0; c < 16; ++c) acc[c] = fmaf(wB, fB[c], acc[c]);
        }
    }

    // fold the 8 groups (lanes g*8+l8 share cols [l8*16, l8*16+16))
    #pragma unroll
    for (int c = 0; c < 16; ++c) {
        acc[c] += __shfl_xor(acc[c], 8);
        acc[c] += __shfl_xor(acc[c], 16);
        acc[c] += __shfl_xor(acc[c], 32);
    }

    if (g == 0) {
        bf16x8 p0, p1;
        #pragma unroll
        for (int c = 0; c < 8; ++c) {
            p0[c] = (short)f2bf(acc[c]);
            p1[c] = (short)f2bf(acc[c + 8]);
        }
        short* dstp = aggHi + (size_t)wave * D + l8 * 16;
        *(bf16x8*)dstp = p0;
        *(bf16x8*)(dstp + 8) = p1;
    }
}

// ---------------------------------------------------------------------------
// MFMA GEMM, 128-row tile, single bf16 W plane:
//   acc = agg@Wrel + h@Wroot   (K=256 concat, one LDS stage, 2 segments).
// Epilogue: layer<L-1 -> AhN bf16 + AhN8 fp8 (relu); last -> fp32 d_out.
// ---------------------------------------------------------------------------
#define STAGE_W(WSRC)                                                           \
    _Pragma("unroll")                                                           \
    for (int r = 0; r < 16; ++r) {                                              \
        int u = r * 256 + tid;                                                  \
        bf16x8 v = *(const bf16x8*)((WSRC) + (size_t)u * 8);                    \
        int scol = u >> 5, sku = u & 31;                                        \
        *(bf16x8*)((char*)bsh + scol * 512 + ((sku ^ (scol & 7)) << 4)) = v;    \
    }

#define MFMA_SEG(APTR, KUOFF)                                                   \
    _Pragma("unroll")                                                           \
    for (int ks = 0; ks < 4; ++ks) {                                            \
        bf16x8 av[4];                                                           \
        _Pragma("unroll")                                                       \
        for (int m = 0; m < 4; ++m)                                             \
            av[m] = *(const bf16x8*)((APTR) + abase + (size_t)m * 16 * D        \
                                     + ks * 32 + l4 * 8);                       \
        _Pragma("unroll")                                                       \
        for (int n = 0; n < 4; ++n) {                                           \
            int col = wc * 64 + n * 16 + l15;                                   \
            int ku = (KUOFF) + ks * 4 + l4;                                     \
            bf16x8 b = *(const bf16x8*)((const char*)bsh + col * 512            \
                                        + ((ku ^ (col & 7)) << 4));             \
            _Pragma("unroll")                                                   \
            for (int m = 0; m < 4; ++m)                                         \
                acc[m][n] = __builtin_amdgcn_mfma_f32_16x16x32_bf16(            \
                    av[m], b, acc[m][n], 0, 0, 0);                              \
        }                                                                       \
    }

__global__ __launch_bounds__(256, 2) void gemm_mfma(
    const short* __restrict__ aggHi,
    const short* __restrict__ Ah, short* __restrict__ AhN,
    unsigned char* __restrict__ AhN8,
    const short* __restrict__ WT,
    const float* __restrict__ bias, float* __restrict__ outf,
    int N, int relu, int writef)
{
    __shared__ short bsh[32768];   // 64 KB: [128 cols][256 k] bf16, swizzled
    int tid = threadIdx.x;
    int lane = tid & 63;
    int wid = tid >> 6;
    int wr = wid >> 1, wc = wid & 1;
    int l15 = lane & 15, l4 = lane >> 4;
    int row0 = blockIdx.x * 128;

    size_t abase = (size_t)(row0 + wr * 64 + l15) * D;

    f32x4 acc[4][4];
    #pragma unroll
    for (int m = 0; m < 4; ++m)
        #pragma unroll
        for (int n = 0; n < 4; ++n)
            acc[m][n] = (f32x4){0.f, 0.f, 0.f, 0.f};

    STAGE_W(WT);
    __syncthreads();
    MFMA_SEG(aggHi, 0);    // agg @ Wrel
    MFMA_SEG(Ah, 16);      // h @ Wroot

    #pragma unroll
    for (int n = 0; n < 4; ++n) {
        int col = wc * 64 + n * 16 + l15;
        float bv = bias[col];
        #pragma unroll
        for (int m = 0; m < 4; ++m) {
            #pragma unroll
            for (int r = 0; r < 4; ++r) {
                int row = row0 + wr * 64 + m * 16 + l4 * 4 + r;
                if (row < N) {
                    float v = acc[m][n][r] + bv;
                    if (relu) v = fmaxf(v, 0.f);
                    if (writef) {
                        outf[(size_t)row * D + col] = v;
                    } else {
                        AhN[(size_t)row * D + col] = (short)f2bf(v);
                        AhN8[(size_t)row * D + col] = f2fp8(v);
                    }
                }
            }
        }
    }
}

// ---------------------------------------------------------------------------
extern "C" void kernel_launch(void* const* d_in, const int* in_sizes, int n_in,
                              void* d_out, int out_size, void* d_ws, size_t ws_size,
                              hipStream_t stream)
{
    const float* x     = (const float*)d_in[0];
    const int*   ei    = (const int*)d_in[1];
    const float* ew    = (const float*)d_in[2];
    const float* Wrel  = (const float*)d_in[3];
    const float* brel  = (const float*)d_in[4];
    const float* Wroot = (const float*)d_in[5];
    float* out = (float*)d_out;

    int N = in_sizes[0] / D;     // 50000 (< 65536: required by 4B edge pack)
    int E = in_sizes[2];
    int L = in_sizes[3] / (D * D);
    int Npad = ((N + 127) / 128) * 128;   // 128-row gemm tiles
    const int* src = ei;
    const int* dst = ei + E;
    int nb = (N + 255) / 256;

    // Workspace layout
    short* Ah0   = (short*)d_ws;                        // Npad*128 bf16
    short* Ah1   = Ah0 + (size_t)Npad * D;              // Npad*128 bf16
    short* aggHi = Ah1 + (size_t)Npad * D;              // Npad*128 bf16
    short* WT    = aggHi + (size_t)Npad * D;            // L*32768 bf16
    unsigned* edata = (unsigned*)(WT + (size_t)L * 32768); // E u32
    int*   row_ptr = (int*)(edata + E);                 // N+1
    int*   rank    = row_ptr + (N + 1);                 // E
    int*   counts  = rank + E;                          // N
    int*   bsums   = counts + N;                        // nb
    unsigned char* Ah8_0 = (unsigned char*)(bsums + nb);     // Npad*128 fp8
    unsigned char* Ah8_1 = Ah8_0 + (size_t)Npad * D;         // Npad*128 fp8

    dim3 blk256(256);
    dim3 grdE((E + 255) / 256);
    dim3 grdN(nb);
    int nchunks = (E + 256 * SC_IT - 1) / (256 * SC_IT);
    dim3 grdScat(nchunks * 8);
    dim3 grdGather((N * 64 + 255) / 256);
    dim3 grdGemm(Npad / 128);
    dim3 grdCX((N * 64 + 255) / 256);
    dim3 grdCW((L * 32768 + 255) / 256);

    // --- CSR build (once) ---
    hipMemsetAsync(counts, 0, (size_t)N * sizeof(int), stream);
    rank_kernel<<<grdE, blk256, 0, stream>>>(dst, counts, rank, E);
    blocksum_kernel<<<grdN, blk256, 0, stream>>>(counts, bsums, N);
    scansums_kernel<<<1, blk256, 0, stream>>>(bsums, nb);
    emit_kernel<<<grdN, blk256, 0, stream>>>(counts, bsums, row_ptr, N, E);
    scatter_xcd_kernel<<<grdScat, blk256, 0, stream>>>(src, dst, ew, row_ptr,
                                                       rank, edata, E, N);

    // --- conversions (once) ---
    convert_w_kernel<<<grdCW, blk256, 0, stream>>>(Wrel, Wroot, WT, L * 32768);
    convert_x_kernel<<<grdCX, blk256, 0, stream>>>(x, Ah0, Ah8_0, N);

    // --- layers (ping-pong h buffers) ---
    for (int l = 0; l < L; ++l) {
        const short* Ain = (l & 1) ? Ah1 : Ah0;
        short* Aout      = (l & 1) ? Ah0 : Ah1;
        const unsigned char* Ain8 = (l & 1) ? Ah8_1 : Ah8_0;
        unsigned char* Aout8      = (l & 1) ? Ah8_0 : Ah8_1;
        gather_fp8<<<grdGather, blk256, 0, stream>>>(Ain8, aggHi, edata, row_ptr, N);
        gemm_mfma<<<grdGemm, blk256, 0, stream>>>(
            aggHi, Ain, Aout, Aout8, WT + (size_t)l * 32768,
            brel + (size_t)l * D, out, N, (l < L - 1) ? 1 : 0, (l == L - 1) ? 1 : 0);
    }
}

// Round 19
// 236.389 us; speedup vs baseline: 1.1151x; 1.1151x over previous
//
#include <hip/hip_runtime.h>

#define D 128
#define SC_IT 16   // edges per thread in scatter chunk (strided by 256)

typedef __attribute__((ext_vector_type(8))) short bf16x8;
typedef __attribute__((ext_vector_type(4))) float f32x4;
typedef __attribute__((ext_vector_type(4))) int   int4v;

__device__ __forceinline__ float uif(unsigned u) { return __uint_as_float(u); }
__device__ __forceinline__ unsigned short f2bf(float f) {
    unsigned u = __float_as_uint(f);
    u += 0x7fffu + ((u >> 16) & 1u);     // RNE to bf16
    return (unsigned short)(u >> 16);
}
__device__ __forceinline__ float bf2f(unsigned short h) {
    return __uint_as_float(((unsigned)h) << 16);
}

// ---------------------------------------------------------------------------
// CSR build: rank histogram -> scan -> XCD-partitioned ATOMIC-FREE scatter
// edata entry: bits[15:0] = src (N < 65536), bits[31:16] = bf16(w).
// ---------------------------------------------------------------------------
__global__ __launch_bounds__(256) void rank_kernel(
    const int* __restrict__ dst, int* __restrict__ counts,
    int* __restrict__ rank, int E)
{
    int base = (blockIdx.x * 256 + threadIdx.x) * 4;
    if (base >= E) return;
    if (base + 4 <= E) {
        int4v d = *(const int4v*)(dst + base);
        int4v r;
        r.x = atomicAdd(&counts[d.x], 1);
        r.y = atomicAdd(&counts[d.y], 1);
        r.z = atomicAdd(&counts[d.z], 1);
        r.w = atomicAdd(&counts[d.w], 1);
        *(int4v*)(rank + base) = r;
    } else {
        for (int e = base; e < E; ++e) rank[e] = atomicAdd(&counts[dst[e]], 1);
    }
}

__global__ __launch_bounds__(256) void blocksum_kernel(
    const int* __restrict__ counts, int* __restrict__ bsums, int N)
{
    __shared__ int red[256];
    int t = threadIdx.x;
    int i = blockIdx.x * 256 + t;
    red[t] = (i < N) ? counts[i] : 0;
    __syncthreads();
    #pragma unroll
    for (int off = 128; off > 0; off >>= 1) {
        if (t < off) red[t] += red[t + off];
        __syncthreads();
    }
    if (t == 0) bsums[blockIdx.x] = red[0];
}

__global__ __launch_bounds__(256) void scansums_kernel(
    int* __restrict__ bsums, int nb)
{
    __shared__ int s[256];
    int t = threadIdx.x;
    int v = (t < nb) ? bsums[t] : 0;
    s[t] = v;
    __syncthreads();
    #pragma unroll
    for (int off = 1; off < 256; off <<= 1) {
        int tmp = (t >= off) ? s[t - off] : 0;
        __syncthreads();
        s[t] += tmp;
        __syncthreads();
    }
    if (t < nb) bsums[t] = s[t] - v;
}

__global__ __launch_bounds__(256) void emit_kernel(
    const int* __restrict__ counts, const int* __restrict__ bsums,
    int* __restrict__ row_ptr, int N, int E)
{
    __shared__ int s[256];
    int t = threadIdx.x;
    int i = blockIdx.x * 256 + t;
    int v = (i < N) ? counts[i] : 0;
    s[t] = v;
    __syncthreads();
    #pragma unroll
    for (int off = 1; off < 256; off <<= 1) {
        int tmp = (t >= off) ? s[t - off] : 0;
        __syncthreads();
        s[t] += tmp;
        __syncthreads();
    }
    int excl = s[t] - v + bsums[blockIdx.x];
    if (i < N) row_ptr[i] = excl;
    if (blockIdx.x == 0 && t == 0) row_ptr[N] = E;
}

// XCD-partitioned atomic-free scatter: xcd = blockIdx&7 owns one dst slice;
// lane->edge mapping is stride-1 across the wave (R12 lesson: keeps the
// ~1/8-filtered claimed reads line-coalesced).
__global__ __launch_bounds__(256) void scatter_xcd_kernel(
    const int* __restrict__ src, const int* __restrict__ dst,
    const float* __restrict__ ew, const int* __restrict__ row_ptr,
    const int* __restrict__ rank, unsigned* __restrict__ edata, int E, int N)
{
    int xcd   = blockIdx.x & 7;
    int chunk = blockIdx.x >> 3;
    int lo = (int)(((long long)xcd * N) >> 3);
    int hi = (int)(((long long)(xcd + 1) * N) >> 3);
    int base = chunk * (256 * SC_IT) + threadIdx.x;
    #pragma unroll
    for (int it = 0; it < SC_IT; ++it) {
        int e = base + it * 256;
        if (e < E) {
            int d = __builtin_nontemporal_load(&dst[e]);
            if (d >= lo && d < hi) {
                int pos = row_ptr[d] + rank[e];
                unsigned pk = (unsigned)(unsigned short)
                                  __builtin_nontemporal_load(&src[e])
                            | ((unsigned)f2bf(
                                  __builtin_nontemporal_load(&ew[e])) << 16);
                edata[pos] = pk;
            }
        }
    }
}

// ---------------------------------------------------------------------------
// Converts. h buffer: compact [Npad][128] bf16 (ping-pong Ah0/Ah1).
// WT layout: [L][128 cols][256 k] bf16; k 0-127 = Wrel rows, 128-255 = Wroot.
// Single bf16 plane (W_lo dropped R15: error ~0.02 << 0.25 harness floor).
// ---------------------------------------------------------------------------
__global__ __launch_bounds__(256) void convert_x_kernel(
    const float* __restrict__ x, short* __restrict__ Ah, int N)
{
    int t = blockIdx.x * 256 + threadIdx.x;   // over N*64 (pairs of cols)
    if (t >= N * 64) return;
    int row = t >> 6;
    int c2  = (t & 63) * 2;
    float2 v = *(const float2*)(x + (size_t)row * D + c2);
    *(unsigned*)(Ah + (size_t)row * D + c2) =
        ((unsigned)f2bf(v.y) << 16) | f2bf(v.x);
}

__global__ __launch_bounds__(256) void convert_w_kernel(
    const float* __restrict__ Wrel, const float* __restrict__ Wroot,
    short* __restrict__ WT, int total)
{
    int t = blockIdx.x * 256 + threadIdx.x;   // over L*32768
    if (t >= total) return;
    int l = t >> 15;
    int rem = t & 32767;
    int k = rem >> 7;
    int c = rem & 127;
    float f = (k < 128) ? Wrel[(size_t)l * 16384 + k * D + c]
                        : Wroot[(size_t)l * 16384 + (k - 128) * D + c];
    WT[(size_t)l * 32768 + c * 256 + k] = (short)f2bf(f);
}

// ---------------------------------------------------------------------------
// Aggregation: one wave per node, 4 x 16-lane groups; group g loads a whole
// 256B h row as dwordx4/lane; 4 edge-rows in flight per group (j += 16).
// CONVERGENT inner loop (R6 lesson). Packed 4B edges: src=lo16, bf16 w=hi16.
// Writes compact aggHi [Npad][128] bf16.
// R17/R18 bracketing: this phase is at its interconnect-latency floor —
// halving bytes (fp8) was neutral, halving requests (8-lane) regressed.
// ---------------------------------------------------------------------------
__global__ __launch_bounds__(256) void gather_bf16(
    const short* __restrict__ Ah, short* __restrict__ aggHi,
    const unsigned* __restrict__ edata, const int* __restrict__ row_ptr, int N)
{
    int wave = (blockIdx.x * 256 + threadIdx.x) >> 6;
    int lane = threadIdx.x & 63;
    if (wave >= N) return;
    int g   = lane >> 4;        // group 0..3
    int l16 = lane & 15;        // lane within group
    int beg = row_ptr[wave];
    int cnt = row_ptr[wave + 1] - beg;

    const short* hbase = Ah + l16 * 8;   // this lane's 8 cols

    float acc[8];
    #pragma unroll
    for (int c = 0; c < 8; ++c) acc[c] = 0.f;

    for (int base = 0; base < cnt; base += 64) {
        int k = base + lane;
        int ed = 0;                              // padding: src=0, w=+0.0f
        if (k < cnt) ed = (int)edata[beg + k];
        int m = min(64, cnt - base);
        // convergent: j <= 48, so j+12+g <= 63 is a valid lane; edges past m
        // come from padding lanes (w=0) and contribute nothing.
        for (int j = 0; j < m; j += 16) {
            int eA = __shfl(ed, j + g);
            int eB = __shfl(ed, j + 4 + g);
            int eC = __shfl(ed, j + 8 + g);
            int eD = __shfl(ed, j + 12 + g);
            float wA = uif((unsigned)eA & 0xffff0000u);
            float wB = uif((unsigned)eB & 0xffff0000u);
            float wC = uif((unsigned)eC & 0xffff0000u);
            float wD = uif((unsigned)eD & 0xffff0000u);
            bf16x8 rA = *(const bf16x8*)(hbase + (size_t)(eA & 0xffff) * D);
            bf16x8 rB = *(const bf16x8*)(hbase + (size_t)(eB & 0xffff) * D);
            bf16x8 rC = *(const bf16x8*)(hbase + (size_t)(eC & 0xffff) * D);
            bf16x8 rD = *(const bf16x8*)(hbase + (size_t)(eD & 0xffff) * D);
            #pragma unroll
            for (int c = 0; c < 8; ++c)
                acc[c] = fmaf(wA, bf2f((unsigned short)rA[c]), acc[c]);
            #pragma unroll
            for (int c = 0; c < 8; ++c)
                acc[c] = fmaf(wB, bf2f((unsigned short)rB[c]), acc[c]);
            #pragma unroll
            for (int c = 0; c < 8; ++c)
                acc[c] = fmaf(wC, bf2f((unsigned short)rC[c]), acc[c]);
            #pragma unroll
            for (int c = 0; c < 8; ++c)
                acc[c] = fmaf(wD, bf2f((unsigned short)rD[c]), acc[c]);
        }
    }

    #pragma unroll
    for (int c = 0; c < 8; ++c) {
        acc[c] += __shfl_xor(acc[c], 16);
        acc[c] += __shfl_xor(acc[c], 32);
    }

    if (g == 0) {
        bf16x8 pk;
        #pragma unroll
        for (int c = 0; c < 8; ++c) pk[c] = (short)f2bf(acc[c]);
        *(bf16x8*)(aggHi + (size_t)wave * D + l16 * 8) = pk;
    }
}

// ---------------------------------------------------------------------------
// MFMA GEMM, 128-row tile, single bf16 W plane:
//   acc = agg@Wrel + h@Wroot   (K=256 concat, one LDS stage, 2 segments).
// Block: 128 rows x 128 cols, 4 waves (2x2), wave tile 64x64 (acc 4x4 f32x4).
// Tail rows (N..Npad) hold stale finite bf16 garbage; stores guarded row<N.
// ---------------------------------------------------------------------------
#define STAGE_W(WSRC)                                                           \
    _Pragma("unroll")                                                           \
    for (int r = 0; r < 16; ++r) {                                              \
        int u = r * 256 + tid;                                                  \
        bf16x8 v = *(const bf16x8*)((WSRC) + (size_t)u * 8);                    \
        int scol = u >> 5, sku = u & 31;                                        \
        *(bf16x8*)((char*)bsh + scol * 512 + ((sku ^ (scol & 7)) << 4)) = v;    \
    }

// A from compact [Npad][128] buffer APTR, W k-chunks ku = KUOFF + ks*4 + l4
#define MFMA_SEG(APTR, KUOFF)                                                   \
    _Pragma("unroll")                                                           \
    for (int ks = 0; ks < 4; ++ks) {                                            \
        bf16x8 av[4];                                                           \
        _Pragma("unroll")                                                       \
        for (int m = 0; m < 4; ++m)                                             \
            av[m] = *(const bf16x8*)((APTR) + abase + (size_t)m * 16 * D        \
                                     + ks * 32 + l4 * 8);                       \
        _Pragma("unroll")                                                       \
        for (int n = 0; n < 4; ++n) {                                           \
            int col = wc * 64 + n * 16 + l15;                                   \
            int ku = (KUOFF) + ks * 4 + l4;                                     \
            bf16x8 b = *(const bf16x8*)((const char*)bsh + col * 512            \
                                        + ((ku ^ (col & 7)) << 4));             \
            _Pragma("unroll")                                                   \
            for (int m = 0; m < 4; ++m)                                         \
                acc[m][n] = __builtin_amdgcn_mfma_f32_16x16x32_bf16(            \
                    av[m], b, acc[m][n], 0, 0, 0);                              \
        }                                                                       \
    }

__global__ __launch_bounds__(256, 2) void gemm_mfma(
    const short* __restrict__ aggHi,
    const short* __restrict__ Ah, short* __restrict__ AhN,
    const short* __restrict__ WT,
    const float* __restrict__ bias, float* __restrict__ outf,
    int N, int relu, int writef)
{
    __shared__ short bsh[32768];   // 64 KB: [128 cols][256 k] bf16, swizzled
    int tid = threadIdx.x;
    int lane = tid & 63;
    int wid = tid >> 6;
    int wr = wid >> 1, wc = wid & 1;
    int l15 = lane & 15, l4 = lane >> 4;
    int row0 = blockIdx.x * 128;

    size_t abase = (size_t)(row0 + wr * 64 + l15) * D;

    f32x4 acc[4][4];
    #pragma unroll
    for (int m = 0; m < 4; ++m)
        #pragma unroll
        for (int n = 0; n < 4; ++n)
            acc[m][n] = (f32x4){0.f, 0.f, 0.f, 0.f};

    STAGE_W(WT);
    __syncthreads();
    MFMA_SEG(aggHi, 0);    // agg @ Wrel
    MFMA_SEG(Ah, 16);      // h @ Wroot

    #pragma unroll
    for (int n = 0; n < 4; ++n) {
        int col = wc * 64 + n * 16 + l15;
        float bv = bias[col];
        #pragma unroll
        for (int m = 0; m < 4; ++m) {
            #pragma unroll
            for (int r = 0; r < 4; ++r) {
                int row = row0 + wr * 64 + m * 16 + l4 * 4 + r;
                if (row < N) {
                    float v = acc[m][n][r] + bv;
                    if (relu) v = fmaxf(v, 0.f);
                    if (writef) outf[(size_t)row * D + col] = v;
                    else        AhN[(size_t)row * D + col] = (short)f2bf(v);
                }
            }
        }
    }
}

// ---------------------------------------------------------------------------
extern "C" void kernel_launch(void* const* d_in, const int* in_sizes, int n_in,
                              void* d_out, int out_size, void* d_ws, size_t ws_size,
                              hipStream_t stream)
{
    const float* x     = (const float*)d_in[0];
    const int*   ei    = (const int*)d_in[1];
    const float* ew    = (const float*)d_in[2];
    const float* Wrel  = (const float*)d_in[3];
    const float* brel  = (const float*)d_in[4];
    const float* Wroot = (const float*)d_in[5];
    float* out = (float*)d_out;

    int N = in_sizes[0] / D;     // 50000 (< 65536: required by 4B edge pack)
    int E = in_sizes[2];
    int L = in_sizes[3] / (D * D);
    int Npad = ((N + 127) / 128) * 128;   // 128-row gemm tiles
    const int* src = ei;
    const int* dst = ei + E;
    int nb = (N + 255) / 256;

    // Workspace layout (compact [Npad][128] bf16 planes)
    short* Ah0   = (short*)d_ws;                        // Npad*128
    short* Ah1   = Ah0 + (size_t)Npad * D;              // Npad*128
    short* aggHi = Ah1 + (size_t)Npad * D;              // Npad*128
    short* WT    = aggHi + (size_t)Npad * D;            // L*32768
    unsigned* edata = (unsigned*)(WT + (size_t)L * 32768); // E u32
    int*   row_ptr = (int*)(edata + E);                 // N+1
    int*   rank    = row_ptr + (N + 1);                 // E
    int*   counts  = rank + E;                          // N
    int*   bsums   = counts + N;                        // nb

    dim3 blk256(256);
    dim3 grdH((E + 1023) / 1024);
    dim3 grdN(nb);
    int nchunks = (E + 256 * SC_IT - 1) / (256 * SC_IT);
    dim3 grdScat(nchunks * 8);
    dim3 grdGather((N * 64 + 255) / 256);
    dim3 grdGemm(Npad / 128);
    dim3 grdCX((N * 64 + 255) / 256);
    dim3 grdCW((L * 32768 + 255) / 256);

    // --- CSR build (once) ---
    hipMemsetAsync(counts, 0, (size_t)N * sizeof(int), stream);
    rank_kernel<<<grdH, blk256, 0, stream>>>(dst, counts, rank, E);
    blocksum_kernel<<<grdN, blk256, 0, stream>>>(counts, bsums, N);
    scansums_kernel<<<1, blk256, 0, stream>>>(bsums, nb);
    emit_kernel<<<grdN, blk256, 0, stream>>>(counts, bsums, row_ptr, N, E);
    scatter_xcd_kernel<<<grdScat, blk256, 0, stream>>>(src, dst, ew, row_ptr,
                                                       rank, edata, E, N);

    // --- conversions (once) ---
    convert_w_kernel<<<grdCW, blk256, 0, stream>>>(Wrel, Wroot, WT, L * 32768);
    convert_x_kernel<<<grdCX, blk256, 0, stream>>>(x, Ah0, N);

    // --- layers (ping-pong h buffers) ---
    for (int l = 0; l < L; ++l) {
        const short* Ain  = (l & 1) ? Ah1 : Ah0;
        short*       Aout = (l & 1) ? Ah0 : Ah1;
        gather_bf16<<<grdGather, blk256, 0, stream>>>(Ain, aggHi, edata, row_ptr, N);
        gemm_mfma<<<grdGemm, blk256, 0, stream>>>(
            aggHi, Ain, Aout, WT + (size_t)l * 32768,
            brel + (size_t)l * D, out, N, (l < L - 1) ? 1 : 0, (l == L - 1) ? 1 : 0);
    }
}